// Round 1
// baseline (54.991 us; speedup 1.0000x reference)
//
#include <hip/hip_runtime.h>
#include <math.h>

#define N1 8192
#define N2 4096
#define N3 2048

// ---------- Kernel 1: l1 = 0.95*l1_state + 0.05*tanh(smi) ----------
__global__ __launch_bounds__(256) void k_l1(const float* __restrict__ smi,
                                            const float* __restrict__ l1s,
                                            float* __restrict__ l1) {
    int i = blockIdx.x * 256 + threadIdx.x;
    if (i < N1) l1[i] = 0.95f * l1s[i] + 0.05f * tanhf(smi[i]);
}

// ---------- Kernel 2: one block per row of w12/w32 ----------
// l2[r] = 0.98*l2_state[r] + 0.02*tanh( w12[r,:]@l1 + 0.3*(w32[r,:]@l3_state) )
__global__ __launch_bounds__(256) void k_l2(const float* __restrict__ w12,
                                            const float* __restrict__ w32,
                                            const float* __restrict__ l1,
                                            const float* __restrict__ l3s,
                                            const float* __restrict__ l2s,
                                            float* __restrict__ l2) {
    __shared__ float ws[4];
    const int r = blockIdx.x;
    const int t = threadIdx.x;
    const float4* __restrict__ w12r = reinterpret_cast<const float4*>(w12) + (size_t)r * (N1 / 4);
    const float4* __restrict__ w32r = reinterpret_cast<const float4*>(w32) + (size_t)r * (N3 / 4);
    const float4* __restrict__ x1 = reinterpret_cast<const float4*>(l1);
    const float4* __restrict__ x3 = reinterpret_cast<const float4*>(l3s);

    float acc = 0.0f;
#pragma unroll
    for (int k = 0; k < (N1 / 4) / 256; ++k) {  // 8 iters
        const int i = t + k * 256;
        float4 a = w12r[i];
        float4 b = x1[i];
        acc = fmaf(a.x, b.x, fmaf(a.y, b.y, fmaf(a.z, b.z, fmaf(a.w, b.w, acc))));
    }
    float acc2 = 0.0f;
#pragma unroll
    for (int k = 0; k < (N3 / 4) / 256; ++k) {  // 2 iters
        const int i = t + k * 256;
        float4 a = w32r[i];
        float4 b = x3[i];
        acc2 = fmaf(a.x, b.x, fmaf(a.y, b.y, fmaf(a.z, b.z, fmaf(a.w, b.w, acc2))));
    }
    float v = fmaf(0.3f, acc2, acc);
#pragma unroll
    for (int off = 32; off; off >>= 1) v += __shfl_down(v, off, 64);
    if ((t & 63) == 0) ws[t >> 6] = v;
    __syncthreads();
    if (t == 0) {
        float tot = ws[0] + ws[1] + ws[2] + ws[3];
        l2[r] = 0.98f * l2s[r] + 0.02f * tanhf(tot);
    }
}

// ---------- Kernel 3: one block per row of w23 ----------
// l3[r] = 0.99*l3_state[r] + 0.01*tanh( w23[r,:]@l2 )
__global__ __launch_bounds__(256) void k_l3(const float* __restrict__ w23,
                                            const float* __restrict__ l2,
                                            const float* __restrict__ l3s,
                                            float* __restrict__ l3) {
    __shared__ float ws[4];
    const int r = blockIdx.x;
    const int t = threadIdx.x;
    const float4* __restrict__ wr = reinterpret_cast<const float4*>(w23) + (size_t)r * (N2 / 4);
    const float4* __restrict__ x2 = reinterpret_cast<const float4*>(l2);

    float acc = 0.0f;
#pragma unroll
    for (int k = 0; k < (N2 / 4) / 256; ++k) {  // 4 iters
        const int i = t + k * 256;
        float4 a = wr[i];
        float4 b = x2[i];
        acc = fmaf(a.x, b.x, fmaf(a.y, b.y, fmaf(a.z, b.z, fmaf(a.w, b.w, acc))));
    }
    float v = acc;
#pragma unroll
    for (int off = 32; off; off >>= 1) v += __shfl_down(v, off, 64);
    if ((t & 63) == 0) ws[t >> 6] = v;
    __syncthreads();
    if (t == 0) {
        float tot = ws[0] + ws[1] + ws[2] + ws[3];
        l3[r] = 0.99f * l3s[r] + 0.01f * tanhf(tot);
    }
}

// ---------- Kernel 4: all scalar reductions, single block ----------
// moments: [0]=sum|v| [1]=sum v [2]=sum v^2 over all 14336
//          [3..7]  = sx, sy, sxx, syy, sxy over (l1[:4096], l2)
//          [8..12] = sx, sy, sxx, syy, sxy over (l2[:2048], l3)
__global__ __launch_bounds__(1024) void k_fin(const float* __restrict__ out,
                                              const float* __restrict__ corr_in,
                                              const float* __restrict__ coh_in,
                                              float* __restrict__ scal) {
    __shared__ double ws[16];
    const float* l1 = out;
    const float* l2 = out + N1;
    const float* l3 = out + N1 + N2;
    const int t = threadIdx.x;

    double p[13];
#pragma unroll
    for (int j = 0; j < 13; ++j) p[j] = 0.0;

    for (int i = t; i < N1 + N2 + N3; i += 1024) {
        double v = (double)out[i];
        p[0] += fabs(v);
        p[1] += v;
        p[2] += v * v;
    }
    for (int i = t; i < N2; i += 1024) {
        double x = (double)l1[i], y = (double)l2[i];
        p[3] += x; p[4] += y; p[5] += x * x; p[6] += y * y; p[7] += x * y;
    }
    for (int i = t; i < N3; i += 1024) {
        double x = (double)l2[i], y = (double)l3[i];
        p[8] += x; p[9] += y; p[10] += x * x; p[11] += y * y; p[12] += x * y;
    }

    double r[13];
#pragma unroll
    for (int j = 0; j < 13; ++j) {
        double v = p[j];
#pragma unroll
        for (int off = 32; off; off >>= 1) v += __shfl_down(v, off, 64);
        __syncthreads();
        if ((t & 63) == 0) ws[t >> 6] = v;
        __syncthreads();
        if (t == 0) {
            double s = 0.0;
            for (int w = 0; w < 16; ++w) s += ws[w];
            r[j] = s;
        }
    }

    if (t == 0) {
        const double n12 = (double)N2;
        const double n23 = (double)N3;
        const double nall = (double)(N1 + N2 + N3);

        double sxy12 = r[7] - r[3] * r[4] / n12;
        double sxx12 = r[5] - r[3] * r[3] / n12;
        double syy12 = r[6] - r[4] * r[4] / n12;
        double den12 = sqrt(sxx12 * syy12);
        double c12 = (den12 > 0.0 && isfinite(den12)) ? sxy12 / den12 : 0.0;

        double sxy23 = r[12] - r[8] * r[9] / n23;
        double sxx23 = r[10] - r[8] * r[8] / n23;
        double syy23 = r[11] - r[9] * r[9] / n23;
        double den23 = sqrt(sxx23 * syy23);
        double c23 = (den23 > 0.0 && isfinite(den23)) ? sxy23 / den23 : 0.0;

        double corr_new = 0.9 * (double)corr_in[0] + 0.1 * (c12 + c23) * 0.5;

        double total = r[0];
        double var = (r[2] - r[1] * r[1] / nall) / (nall - 1.0);
        double coh = total / (var + 1e-6);
        coh = fmin(fmax(coh, 0.0), 10.0);
        double coh_new = 0.9 * (double)coh_in[0] + 0.1 * coh;

        double hier = total / nall;

        scal[0] = (float)corr_new;
        scal[1] = (float)coh_new;
        scal[2] = (float)hier;
    }
}

extern "C" void kernel_launch(void* const* d_in, const int* in_sizes, int n_in,
                              void* d_out, int out_size, void* d_ws, size_t ws_size,
                              hipStream_t stream) {
    const float* smi     = (const float*)d_in[0];
    const float* l1s     = (const float*)d_in[1];
    const float* l2s     = (const float*)d_in[2];
    const float* l3s     = (const float*)d_in[3];
    const float* w12     = (const float*)d_in[4];
    const float* w23     = (const float*)d_in[5];
    const float* w32     = (const float*)d_in[6];
    // d_in[7] = w21 is UNUSED by the reference — never read (saves 134 MB).
    const float* corr_in = (const float*)d_in[8];
    const float* coh_in  = (const float*)d_in[9];

    float* out = (float*)d_out;
    float* l1 = out;
    float* l2 = out + N1;
    float* l3 = out + N1 + N2;
    float* scal = out + N1 + N2 + N3;

    k_l1<<<dim3(N1 / 256), dim3(256), 0, stream>>>(smi, l1s, l1);
    k_l2<<<dim3(N2), dim3(256), 0, stream>>>(w12, w32, l1, l3s, l2s, l2);
    k_l3<<<dim3(N3), dim3(256), 0, stream>>>(w23, l2, l3s, l3);
    k_fin<<<dim3(1), dim3(1024), 0, stream>>>(out, corr_in, coh_in, scal);
}